// Round 1
// baseline (4249.348 us; speedup 1.0000x reference)
//
#include <hip/hip_runtime.h>

#define DD 128
#define NNODES 50000
#define NEDGES 800000
#define BN_EPS 1e-5f

// ---------------------------------------------------------------------------
// Dual GEMM: support = h @ W   ;  acc = h @ SW + b
// h: [n,128], W/SW: [128,128], b: [128]
// Block: 256 threads computes a 64-row x 128-col tile of BOTH outputs.
// Thread tile: 8 rows x 4 cols per output matrix.
// ---------------------------------------------------------------------------
__global__ __launch_bounds__(256) void gemm_dual_kernel(
    const float* __restrict__ h,
    const float* __restrict__ Wl,    // [128][128]
    const float* __restrict__ SWl,   // [128][128]
    const float* __restrict__ bl,    // [128]
    float* __restrict__ support,
    float* __restrict__ acc,
    int n)
{
    __shared__ float hs[64][DD + 4];   // [row][k], pad 4 floats: conflict-free f4 writes
    const int tid  = threadIdx.x;
    const int brow = blockIdx.x * 64;

    // Stage 64x128 input tile. i -> (row = i>>5, k-quad = i&31).
    // Global: lanes read consecutive 16B within a row -> coalesced.
    // LDS: consecutive lanes write consecutive 16B within a row -> conflict-free.
#pragma unroll
    for (int it = 0; it < 8; ++it) {
        int i  = tid + it * 256;       // 0..2047
        int r  = i >> 5;               // 0..63
        int kq = i & 31;               // 0..31
        int gr = brow + r;
        float4 v = make_float4(0.f, 0.f, 0.f, 0.f);
        if (gr < n) v = *(const float4*)(h + (size_t)gr * DD + kq * 4);
        *(float4*)(&hs[r][kq * 4]) = v;
    }
    __syncthreads();

    const int c0 = (tid & 31) * 4;     // output column quad
    const int r0 = (tid >> 5) * 8;     // output row block (8 rows)

    float accW[8][4] = {};
    float accS[8][4] = {};

#pragma unroll 4
    for (int k = 0; k < DD; ++k) {
        const float4 w4 = *(const float4*)(Wl  + k * DD + c0);
        const float4 s4 = *(const float4*)(SWl + k * DD + c0);
        float a[8];
#pragma unroll
        for (int i = 0; i < 8; ++i) a[i] = hs[r0 + i][k];   // broadcast reads
#pragma unroll
        for (int i = 0; i < 8; ++i) {
            accW[i][0] += a[i] * w4.x; accW[i][1] += a[i] * w4.y;
            accW[i][2] += a[i] * w4.z; accW[i][3] += a[i] * w4.w;
            accS[i][0] += a[i] * s4.x; accS[i][1] += a[i] * s4.y;
            accS[i][2] += a[i] * s4.z; accS[i][3] += a[i] * s4.w;
        }
    }

    const float4 bv = *(const float4*)(bl + c0);
#pragma unroll
    for (int i = 0; i < 8; ++i) {
        int gr = brow + r0 + i;
        if (gr < n) {
            *(float4*)(support + (size_t)gr * DD + c0) =
                make_float4(accW[i][0], accW[i][1], accW[i][2], accW[i][3]);
            *(float4*)(acc + (size_t)gr * DD + c0) =
                make_float4(accS[i][0] + bv.x, accS[i][1] + bv.y,
                            accS[i][2] + bv.z, accS[i][3] + bv.w);
        }
    }
}

// ---------------------------------------------------------------------------
// Edge scatter: acc[row[e]][:] += ew[e] * support[col[e]][:]
// Work item = (edge, column-quad). 32 quads of float4 per edge.
// ---------------------------------------------------------------------------
__global__ __launch_bounds__(256) void spmm_scatter_kernel(
    const float* __restrict__ support,
    const int*   __restrict__ row,
    const int*   __restrict__ col,
    const float* __restrict__ ew,
    float* __restrict__ acc,
    int nedges)
{
    const int total  = nedges * 32;            // 25.6M items, fits int
    const int stride = gridDim.x * blockDim.x;
    for (int i = blockIdx.x * blockDim.x + threadIdx.x; i < total; i += stride) {
        const int e = i >> 5;
        const int q = i & 31;
        const int c = col[e];
        const int r = row[e];
        const float w = ew[e];
        const float4 s = *(const float4*)(support + (size_t)c * DD + q * 4);
        float* dst = acc + (size_t)r * DD + q * 4;
        atomicAdd(dst + 0, w * s.x);
        atomicAdd(dst + 1, w * s.y);
        atomicAdd(dst + 2, w * s.z);
        atomicAdd(dst + 3, w * s.w);
    }
}

// ---------------------------------------------------------------------------
// out[i] = h[i] + relu( (acc[i]-rmean)*rsqrt(rvar+eps)*gamma + beta )
// (h == out is fine: pure elementwise, same index)
// ---------------------------------------------------------------------------
__global__ __launch_bounds__(256) void bn_relu_add_kernel(
    const float* __restrict__ h,
    const float* __restrict__ acc,
    const float* __restrict__ gamma,
    const float* __restrict__ beta,
    const float* __restrict__ rmean,
    const float* __restrict__ rvar,
    float* __restrict__ out,
    int n)
{
    const int total  = n * 32;                 // float4 quads
    const int stride = gridDim.x * blockDim.x;
    for (int i = blockIdx.x * blockDim.x + threadIdx.x; i < total; i += stride) {
        const int q = i & 31;
        const float4 a  = *(const float4*)(acc + (size_t)i * 4);
        const float4 hv = *(const float4*)(h   + (size_t)i * 4);
        const float4 g  = *(const float4*)(gamma + q * 4);
        const float4 be = *(const float4*)(beta  + q * 4);
        const float4 m  = *(const float4*)(rmean + q * 4);
        const float4 vv = *(const float4*)(rvar  + q * 4);
        float4 o;
        float t;
        t = (a.x - m.x) * __frsqrt_rn(vv.x + BN_EPS) * g.x + be.x; o.x = hv.x + (t > 0.f ? t : 0.f);
        t = (a.y - m.y) * __frsqrt_rn(vv.y + BN_EPS) * g.y + be.y; o.y = hv.y + (t > 0.f ? t : 0.f);
        t = (a.z - m.z) * __frsqrt_rn(vv.z + BN_EPS) * g.z + be.z; o.z = hv.z + (t > 0.f ? t : 0.f);
        t = (a.w - m.w) * __frsqrt_rn(vv.w + BN_EPS) * g.w + be.w; o.w = hv.w + (t > 0.f ? t : 0.f);
        *(float4*)(out + (size_t)i * 4) = o;
    }
}

extern "C" void kernel_launch(void* const* d_in, const int* in_sizes, int n_in,
                              void* d_out, int out_size, void* d_ws, size_t ws_size,
                              hipStream_t stream) {
    const float* x     = (const float*)d_in[0];
    const int*   row   = (const int*)  d_in[1];
    const int*   col   = (const int*)  d_in[2];
    const float* ew    = (const float*)d_in[3];
    const float* W     = (const float*)d_in[4];   // [6][128][128]
    const float* SW    = (const float*)d_in[5];   // [6][128][128]
    const float* b     = (const float*)d_in[6];   // [6][128]
    const float* gamma = (const float*)d_in[7];
    const float* beta  = (const float*)d_in[8];
    const float* rmean = (const float*)d_in[9];
    const float* rvar  = (const float*)d_in[10];

    float* out     = (float*)d_out;
    float* support = (float*)d_ws;                    // 25.6 MB
    float* acc     = support + (size_t)NNODES * DD;   // 25.6 MB

    // Only layers 0, 2, 5 are live (inner branch layers all consume the
    // branch input x, so only the last layer of each branch reaches output).
    const int layers[3] = {0, 2, 5};

    const int gemm_grid = (NNODES + 63) / 64;   // 782

    const float* h = x;
    for (int li = 0; li < 3; ++li) {
        const int l = layers[li];
        gemm_dual_kernel<<<gemm_grid, 256, 0, stream>>>(
            h, W + (size_t)l * DD * DD, SW + (size_t)l * DD * DD, b + l * DD,
            support, acc, NNODES);
        spmm_scatter_kernel<<<4096, 256, 0, stream>>>(
            support, row, col, ew, acc, NEDGES);
        bn_relu_add_kernel<<<2048, 256, 0, stream>>>(
            h, acc, gamma + l * DD, beta + l * DD, rmean + l * DD, rvar + l * DD,
            out, NNODES);
        h = out;
    }
}

// Round 2
// 448.249 us; speedup vs baseline: 9.4799x; 9.4799x over previous
//
#include <hip/hip_runtime.h>

#define DD 128
#define NNODES 50000
#define NEDGES 800000
#define BN_EPS 1e-5f
#define NBLK_SCAN ((NNODES + 255) / 256)   // 196

// ---------------------------------------------------------------------------
// CSR build: histogram -> two-level exclusive scan -> fill (atomic cursor).
// ---------------------------------------------------------------------------
__global__ __launch_bounds__(256) void hist_kernel(
    const int* __restrict__ row, int* __restrict__ deg, int nedges)
{
    int e = blockIdx.x * 256 + threadIdx.x;
    if (e < nedges) atomicAdd(&deg[row[e]], 1);
}

__global__ __launch_bounds__(256) void scan1_kernel(
    const int* __restrict__ deg, int* __restrict__ excl, int* __restrict__ bsum, int n)
{
    __shared__ int buf[256];
    int i = blockIdx.x * 256 + threadIdx.x;
    int v = (i < n) ? deg[i] : 0;
    buf[threadIdx.x] = v;
    __syncthreads();
#pragma unroll
    for (int off = 1; off < 256; off <<= 1) {
        int t = (threadIdx.x >= off) ? buf[threadIdx.x - off] : 0;
        __syncthreads();
        buf[threadIdx.x] += t;
        __syncthreads();
    }
    if (i < n) excl[i] = buf[threadIdx.x] - v;       // block-local exclusive
    if (threadIdx.x == 255) bsum[blockIdx.x] = buf[255];
}

__global__ __launch_bounds__(256) void scan2_kernel(
    int* __restrict__ bsum, int* __restrict__ boff, int nblk)
{
    __shared__ int buf[256];
    int v = (threadIdx.x < nblk) ? bsum[threadIdx.x] : 0;
    buf[threadIdx.x] = v;
    __syncthreads();
#pragma unroll
    for (int off = 1; off < 256; off <<= 1) {
        int t = (threadIdx.x >= off) ? buf[threadIdx.x - off] : 0;
        __syncthreads();
        buf[threadIdx.x] += t;
        __syncthreads();
    }
    if (threadIdx.x < nblk) boff[threadIdx.x] = buf[threadIdx.x] - v;
}

__global__ __launch_bounds__(256) void scan3_kernel(
    int* __restrict__ rowptr /*holds excl*/, const int* __restrict__ boff,
    int* __restrict__ cursor, int n)
{
    int i = blockIdx.x * 256 + threadIdx.x;
    if (i < n) {
        int v = rowptr[i] + boff[blockIdx.x];
        rowptr[i] = v;
        cursor[i] = v;
    }
    if (i == 0) rowptr[n] = NEDGES;
}

__global__ __launch_bounds__(256) void csr_fill_kernel(
    const int* __restrict__ row, const int* __restrict__ col,
    const float* __restrict__ ew, int* __restrict__ cursor,
    int* __restrict__ ccol, float* __restrict__ cw, int nedges)
{
    int e = blockIdx.x * 256 + threadIdx.x;
    if (e < nedges) {
        int r = row[e];
        int p = atomicAdd(&cursor[r], 1);
        ccol[p] = col[e];
        cw[p]   = ew[e];
    }
}

// ---------------------------------------------------------------------------
// CSR gather: agg[n][:] = sum_{e in row n} w_e * h[col_e][:]
// One wave per node; lane owns 2 columns (float2). No atomics.
// ---------------------------------------------------------------------------
__global__ __launch_bounds__(256) void spmm_gather_kernel(
    const float* __restrict__ h, const int* __restrict__ rowptr,
    const int* __restrict__ ccol, const float* __restrict__ cw,
    float* __restrict__ agg, int n)
{
    int node = blockIdx.x * 4 + (threadIdx.x >> 6);
    if (node >= n) return;
    const int lane = threadIdx.x & 63;
    const int beg = rowptr[node];
    const int end = rowptr[node + 1];

    float accx = 0.f, accy = 0.f;
    int j = beg;
    for (; j + 4 <= end; j += 4) {
        int   c0 = ccol[j],   c1 = ccol[j+1], c2 = ccol[j+2], c3 = ccol[j+3];
        float w0 = cw[j],     w1 = cw[j+1],   w2 = cw[j+2],   w3 = cw[j+3];
        float2 v0 = *(const float2*)(h + (size_t)c0 * DD + lane * 2);
        float2 v1 = *(const float2*)(h + (size_t)c1 * DD + lane * 2);
        float2 v2 = *(const float2*)(h + (size_t)c2 * DD + lane * 2);
        float2 v3 = *(const float2*)(h + (size_t)c3 * DD + lane * 2);
        accx += w0 * v0.x + w1 * v1.x + w2 * v2.x + w3 * v3.x;
        accy += w0 * v0.y + w1 * v1.y + w2 * v2.y + w3 * v3.y;
    }
    for (; j < end; ++j) {
        int c = ccol[j];
        float w = cw[j];
        float2 v = *(const float2*)(h + (size_t)c * DD + lane * 2);
        accx += w * v.x;
        accy += w * v.y;
    }
    *(float2*)(agg + (size_t)node * DD + lane * 2) = make_float2(accx, accy);
}

// ---------------------------------------------------------------------------
// Fused: out = h + relu( BN( agg@W + h@SW + b ) )
// 64-row tile, single LDS buffer used for two passes (agg, then h).
// After pass 2 the LDS tile holds h -> reused for the residual.
// ---------------------------------------------------------------------------
__global__ __launch_bounds__(256) void gemm_bn_kernel(
    const float* __restrict__ h, const float* __restrict__ agg,
    const float* __restrict__ Wl, const float* __restrict__ SWl,
    const float* __restrict__ bl, const float* __restrict__ gammal,
    const float* __restrict__ betal, const float* __restrict__ rmeanl,
    const float* __restrict__ rvarl,
    float* __restrict__ out, int n)
{
    __shared__ float ts[64][DD + 4];
    const int tid  = threadIdx.x;
    const int brow = blockIdx.x * 64;
    const int c0 = (tid & 31) * 4;
    const int r0 = (tid >> 5) * 8;

    float acc[8][4] = {};

    // ---- pass 1: acc += agg @ W ----
#pragma unroll
    for (int it = 0; it < 8; ++it) {
        int i = tid + it * 256, r = i >> 5, kq = i & 31, gr = brow + r;
        float4 v = make_float4(0.f, 0.f, 0.f, 0.f);
        if (gr < n) v = *(const float4*)(agg + (size_t)gr * DD + kq * 4);
        *(float4*)(&ts[r][kq * 4]) = v;
    }
    __syncthreads();
#pragma unroll 4
    for (int k = 0; k < DD; ++k) {
        const float4 w4 = *(const float4*)(Wl + k * DD + c0);
        float a[8];
#pragma unroll
        for (int i = 0; i < 8; ++i) a[i] = ts[r0 + i][k];
#pragma unroll
        for (int i = 0; i < 8; ++i) {
            acc[i][0] += a[i] * w4.x; acc[i][1] += a[i] * w4.y;
            acc[i][2] += a[i] * w4.z; acc[i][3] += a[i] * w4.w;
        }
    }
    __syncthreads();

    // ---- pass 2: acc += h @ SW ----
#pragma unroll
    for (int it = 0; it < 8; ++it) {
        int i = tid + it * 256, r = i >> 5, kq = i & 31, gr = brow + r;
        float4 v = make_float4(0.f, 0.f, 0.f, 0.f);
        if (gr < n) v = *(const float4*)(h + (size_t)gr * DD + kq * 4);
        *(float4*)(&ts[r][kq * 4]) = v;
    }
    __syncthreads();
#pragma unroll 4
    for (int k = 0; k < DD; ++k) {
        const float4 w4 = *(const float4*)(SWl + k * DD + c0);
        float a[8];
#pragma unroll
        for (int i = 0; i < 8; ++i) a[i] = ts[r0 + i][k];
#pragma unroll
        for (int i = 0; i < 8; ++i) {
            acc[i][0] += a[i] * w4.x; acc[i][1] += a[i] * w4.y;
            acc[i][2] += a[i] * w4.z; acc[i][3] += a[i] * w4.w;
        }
    }

    // ---- epilogue: BN + relu + residual (h tile still in LDS) ----
    const float4 bv = *(const float4*)(bl + c0);
    const float4 g  = *(const float4*)(gammal + c0);
    const float4 be = *(const float4*)(betal + c0);
    const float4 m  = *(const float4*)(rmeanl + c0);
    const float4 vv = *(const float4*)(rvarl + c0);
    const float s0 = g.x * __frsqrt_rn(vv.x + BN_EPS);
    const float s1 = g.y * __frsqrt_rn(vv.y + BN_EPS);
    const float s2 = g.z * __frsqrt_rn(vv.z + BN_EPS);
    const float s3 = g.w * __frsqrt_rn(vv.w + BN_EPS);
    const float h0 = be.x - m.x * s0;
    const float h1 = be.y - m.y * s1;
    const float h2 = be.z - m.z * s2;
    const float h3 = be.w - m.w * s3;

#pragma unroll
    for (int i = 0; i < 8; ++i) {
        int gr = brow + r0 + i;
        if (gr < n) {
            const float4 hv = *(const float4*)(&ts[r0 + i][c0]);
            float t;
            float4 o;
            t = (acc[i][0] + bv.x) * s0 + h0; o.x = hv.x + (t > 0.f ? t : 0.f);
            t = (acc[i][1] + bv.y) * s1 + h1; o.y = hv.y + (t > 0.f ? t : 0.f);
            t = (acc[i][2] + bv.z) * s2 + h2; o.z = hv.z + (t > 0.f ? t : 0.f);
            t = (acc[i][3] + bv.w) * s3 + h3; o.w = hv.w + (t > 0.f ? t : 0.f);
            *(float4*)(out + (size_t)gr * DD + c0) = o;
        }
    }
}

extern "C" void kernel_launch(void* const* d_in, const int* in_sizes, int n_in,
                              void* d_out, int out_size, void* d_ws, size_t ws_size,
                              hipStream_t stream) {
    const float* x     = (const float*)d_in[0];
    const int*   row   = (const int*)  d_in[1];
    const int*   col   = (const int*)  d_in[2];
    const float* ew    = (const float*)d_in[3];
    const float* W     = (const float*)d_in[4];
    const float* SW    = (const float*)d_in[5];
    const float* b     = (const float*)d_in[6];
    const float* gamma = (const float*)d_in[7];
    const float* beta  = (const float*)d_in[8];
    const float* rmean = (const float*)d_in[9];
    const float* rvar  = (const float*)d_in[10];

    float* out = (float*)d_out;

    // workspace layout
    float* agg     = (float*)d_ws;                               // N*128 f32 = 25.6 MB
    int*   rowptr  = (int*)(agg + (size_t)NNODES * DD);          // N+1
    int*   cursor  = rowptr + NNODES + 1;                        // N
    int*   deg     = cursor + NNODES;                            // N
    int*   bsum    = deg + NNODES;                               // 256
    int*   boff    = bsum + 256;                                 // 256
    int*   ccol    = boff + 256;                                 // E
    float* cw      = (float*)(ccol + NEDGES);                    // E

    const int egrid = (NEDGES + 255) / 256;   // 3125

    // ---- build CSR once (row/col/ew are layer-invariant) ----
    hipMemsetAsync(deg, 0, NNODES * sizeof(int), stream);
    hist_kernel<<<egrid, 256, 0, stream>>>(row, deg, NEDGES);
    scan1_kernel<<<NBLK_SCAN, 256, 0, stream>>>(deg, rowptr, bsum, NNODES);
    scan2_kernel<<<1, 256, 0, stream>>>(bsum, boff, NBLK_SCAN);
    scan3_kernel<<<NBLK_SCAN, 256, 0, stream>>>(rowptr, boff, cursor, NNODES);
    csr_fill_kernel<<<egrid, 256, 0, stream>>>(row, col, ew, cursor, ccol, cw, NEDGES);

    // Only layers 0, 2, 5 are live (inner branch layers all consume the
    // branch input, so only each branch's last layer reaches the output).
    const int layers[3] = {0, 2, 5};
    const int ggrid = (NNODES + 3) / 4;       // 12500 (1 wave/node)
    const int mgrid = (NNODES + 63) / 64;     // 782

    const float* h = x;
    for (int li = 0; li < 3; ++li) {
        const int l = layers[li];
        // agg = segment_sum(ew * h[col])  — note (Σ w·h[col])@W == Σ w·(h@W)[col]
        spmm_gather_kernel<<<ggrid, 256, 0, stream>>>(h, rowptr, ccol, cw, agg, NNODES);
        gemm_bn_kernel<<<mgrid, 256, 0, stream>>>(
            h, agg, W + (size_t)l * DD * DD, SW + (size_t)l * DD * DD, b + l * DD,
            gamma + l * DD, beta + l * DD, rmean + l * DD, rvar + l * DD,
            out, NNODES);
        h = out;
    }
}

// Round 3
// 280.898 us; speedup vs baseline: 15.1277x; 1.5958x over previous
//
#include <hip/hip_runtime.h>

#define DD 128
#define NNODES 50000
#define NEDGES 800000
#define BN_EPS 1e-5f
#define NBLK_SCAN ((NNODES + 255) / 256)   // 196

typedef float f32x4 __attribute__((ext_vector_type(4)));
typedef short bf16x8 __attribute__((ext_vector_type(8)));

__device__ __forceinline__ unsigned short f2bf(float f) {
    unsigned u = __float_as_uint(f);
    u = (u + 0x7FFFu + ((u >> 16) & 1u)) >> 16;   // RNE
    return (unsigned short)u;
}
__device__ __forceinline__ float bf2f(unsigned short s) {
    return __uint_as_float((unsigned)s << 16);
}
__device__ __forceinline__ unsigned packbf(float a, float b) {
    return (unsigned)f2bf(a) | ((unsigned)f2bf(b) << 16);
}
__device__ __forceinline__ float lo_bf(unsigned u) { return __uint_as_float(u << 16); }
__device__ __forceinline__ float hi_bf(unsigned u) { return __uint_as_float(u & 0xFFFF0000u); }

// ---------------------------------------------------------------------------
// CSR build: histogram -> two-level exclusive scan -> fill (atomic cursor).
// ---------------------------------------------------------------------------
__global__ __launch_bounds__(256) void hist_kernel(
    const int* __restrict__ row, int* __restrict__ deg, int nedges)
{
    int e = blockIdx.x * 256 + threadIdx.x;
    if (e < nedges) atomicAdd(&deg[row[e]], 1);
}

__global__ __launch_bounds__(256) void scan1_kernel(
    const int* __restrict__ deg, int* __restrict__ excl, int* __restrict__ bsum, int n)
{
    __shared__ int buf[256];
    int i = blockIdx.x * 256 + threadIdx.x;
    int v = (i < n) ? deg[i] : 0;
    buf[threadIdx.x] = v;
    __syncthreads();
#pragma unroll
    for (int off = 1; off < 256; off <<= 1) {
        int t = (threadIdx.x >= off) ? buf[threadIdx.x - off] : 0;
        __syncthreads();
        buf[threadIdx.x] += t;
        __syncthreads();
    }
    if (i < n) excl[i] = buf[threadIdx.x] - v;
    if (threadIdx.x == 255) bsum[blockIdx.x] = buf[255];
}

__global__ __launch_bounds__(256) void scan2_kernel(
    int* __restrict__ bsum, int* __restrict__ boff, int nblk)
{
    __shared__ int buf[256];
    int v = (threadIdx.x < nblk) ? bsum[threadIdx.x] : 0;
    buf[threadIdx.x] = v;
    __syncthreads();
#pragma unroll
    for (int off = 1; off < 256; off <<= 1) {
        int t = (threadIdx.x >= off) ? buf[threadIdx.x - off] : 0;
        __syncthreads();
        buf[threadIdx.x] += t;
        __syncthreads();
    }
    if (threadIdx.x < nblk) boff[threadIdx.x] = buf[threadIdx.x] - v;
}

__global__ __launch_bounds__(256) void scan3_kernel(
    int* __restrict__ rowptr, const int* __restrict__ boff,
    int* __restrict__ cursor, int n)
{
    int i = blockIdx.x * 256 + threadIdx.x;
    if (i < n) {
        int v = rowptr[i] + boff[blockIdx.x];
        rowptr[i] = v;
        cursor[i] = v;
    }
    if (i == 0) rowptr[n] = NEDGES;
}

__global__ __launch_bounds__(256) void csr_fill_kernel(
    const int* __restrict__ row, const int* __restrict__ col,
    const float* __restrict__ ew, int* __restrict__ cursor,
    int* __restrict__ ccol, float* __restrict__ cw, int nedges)
{
    int e = blockIdx.x * 256 + threadIdx.x;
    if (e < nedges) {
        int r = row[e];
        int p = atomicAdd(&cursor[r], 1);
        ccol[p] = col[e];
        cw[p]   = ew[e];
    }
}

// ---------------------------------------------------------------------------
// Converters
// ---------------------------------------------------------------------------
__global__ __launch_bounds__(256) void conv_x16_kernel(
    const float* __restrict__ x, unsigned* __restrict__ h16u, int npairs)
{
    int stride = gridDim.x * 256;
    for (int i = blockIdx.x * 256 + threadIdx.x; i < npairs; i += stride) {
        float2 v = ((const float2*)x)[i];
        h16u[i] = packbf(v.x, v.y);
    }
}

// Wf: MFMA-fragment-ordered [li][ks 0..7][nt 0..7][lane 0..63][i 0..7] bf16
// value = B[k][n] with k = ks*32 + (lane>>4)*8 + i (k<128 -> W, else SW), n = nt*16 + (lane&15)
__global__ __launch_bounds__(256) void conv_wf_kernel(
    const float* __restrict__ W, const float* __restrict__ SW,
    unsigned short* __restrict__ Wf)
{
    int t = blockIdx.x * 256 + threadIdx.x;     // 12288 total
    if (t >= 3 * 8 * 8 * 64) return;
    int lane = t & 63;
    int nt   = (t >> 6) & 7;
    int ks   = (t >> 9) & 7;
    int li   = t >> 12;                          // 0..2
    const int lmap[3] = {0, 2, 5};
    int l = lmap[li];
    int n = nt * 16 + (lane & 15);
    unsigned short* dst = Wf + (((size_t)li * 64 + ks * 8 + nt) * 64 + lane) * 8;
#pragma unroll
    for (int i = 0; i < 8; ++i) {
        int k = ks * 32 + (lane >> 4) * 8 + i;
        float v = (k < 128) ? W[((size_t)l * 128 + k) * 128 + n]
                            : SW[((size_t)l * 128 + (k - 128)) * 128 + n];
        dst[i] = f2bf(v);
    }
}

// ---------------------------------------------------------------------------
// CSR gather (bf16 rows): agg[n][:] = sum_e w_e * h[col_e][:]
// One wave per node; lane owns 2 cols (one packed u32). No atomics.
// ---------------------------------------------------------------------------
__global__ __launch_bounds__(256) void spmm_gather16_kernel(
    const unsigned* __restrict__ h16u, const int* __restrict__ rowptr,
    const int* __restrict__ ccol, const float* __restrict__ cw,
    unsigned* __restrict__ agg16u, int n)
{
    int node = blockIdx.x * 4 + (threadIdx.x >> 6);
    if (node >= n) return;
    const int lane = threadIdx.x & 63;
    const int beg = rowptr[node];
    const int end = rowptr[node + 1];

    float ax = 0.f, ay = 0.f;
    int j = beg;
    for (; j + 4 <= end; j += 4) {
        int   c0 = ccol[j], c1 = ccol[j+1], c2 = ccol[j+2], c3 = ccol[j+3];
        float w0 = cw[j],   w1 = cw[j+1],   w2 = cw[j+2],   w3 = cw[j+3];
        unsigned u0 = h16u[c0 * 64 + lane];
        unsigned u1 = h16u[c1 * 64 + lane];
        unsigned u2 = h16u[c2 * 64 + lane];
        unsigned u3 = h16u[c3 * 64 + lane];
        ax += w0 * lo_bf(u0) + w1 * lo_bf(u1) + w2 * lo_bf(u2) + w3 * lo_bf(u3);
        ay += w0 * hi_bf(u0) + w1 * hi_bf(u1) + w2 * hi_bf(u2) + w3 * hi_bf(u3);
    }
    for (; j < end; ++j) {
        unsigned u = h16u[ccol[j] * 64 + lane];
        float w = cw[j];
        ax += w * lo_bf(u);
        ay += w * hi_bf(u);
    }
    agg16u[node * 64 + lane] = packbf(ax, ay);
}

// ---------------------------------------------------------------------------
// MFMA GEMM: C = [agg|h](N x 256) @ [W;SW](256 x 128), then BN+relu+residual.
// Block: 256 thr (4 waves), BM=64 rows. Wave w owns cols [32w, 32w+32).
// A staged in LDS (bf16, XOR chunk-swizzle); B prefetched from frag-ordered Wf.
// Residual h row read back from the LDS tile (k = 128+col). h16 updated
// in-place (each block writes only rows it staged). Last layer also writes f32.
// ---------------------------------------------------------------------------
__global__ __launch_bounds__(256) void gemm_mfma_kernel(
    unsigned short* __restrict__ h16,        // [n][128] bf16, in-place update
    const unsigned short* __restrict__ agg16,
    const unsigned short* __restrict__ Wf,   // this layer's 32768 ushorts
    const float* __restrict__ bl, const float* __restrict__ gammal,
    const float* __restrict__ betal, const float* __restrict__ rmeanl,
    const float* __restrict__ rvarl,
    float* __restrict__ outf, int n, int write_f32)
{
    __shared__ __align__(16) unsigned short As[64 * 256];   // 32 KB
    const int tid  = threadIdx.x;
    const int lane = tid & 63;
    const int wid  = tid >> 6;
    const int brow = blockIdx.x * 64;

    // ---- B prefetch: 16 frags/wave (8 ksteps x 2 ntiles) ----
    bf16x8 bfr[8][2];
#pragma unroll
    for (int ks = 0; ks < 8; ++ks)
#pragma unroll
        for (int nt2 = 0; nt2 < 2; ++nt2) {
            int nt = wid * 2 + nt2;
            bfr[ks][nt2] = *(const bf16x8*)(Wf + ((size_t)(ks * 8 + nt) * 64 + lane) * 8);
        }

    // ---- stage A tile: 64 rows x 256 bf16 (k<128: agg, k>=128: h) ----
#pragma unroll
    for (int it = 0; it < 8; ++it) {
        int id = tid + it * 256;          // 0..2047
        int r  = id >> 5;                 // 0..63
        int kc = id & 31;                 // 16B chunk (8 bf16)
        int grow = brow + r;
        uint4 v = make_uint4(0, 0, 0, 0);
        if (grow < n) {
            const unsigned short* src = (kc < 16)
                ? (agg16 + (size_t)grow * DD + kc * 8)
                : (h16   + (size_t)grow * DD + (kc - 16) * 8);
            v = *(const uint4*)src;
        }
        int kcs = kc ^ (r & 7);
        *(uint4*)(&As[r * 256 + kcs * 8]) = v;
    }
    __syncthreads();

    // ---- K loop: 8 steps of K=32, 4 m-tiles, 2 n-tiles ----
    f32x4 acc[4][2];
#pragma unroll
    for (int i = 0; i < 4; ++i)
#pragma unroll
        for (int j = 0; j < 2; ++j)
            acc[i][j] = (f32x4){0.f, 0.f, 0.f, 0.f};

#pragma unroll
    for (int ks = 0; ks < 8; ++ks) {
#pragma unroll
        for (int mt = 0; mt < 4; ++mt) {
            int m   = mt * 16 + (lane & 15);
            int kc  = ks * 4 + (lane >> 4);
            int kcs = kc ^ (m & 7);
            bf16x8 afr = *(const bf16x8*)(&As[m * 256 + kcs * 8]);
            acc[mt][0] = __builtin_amdgcn_mfma_f32_16x16x32_bf16(afr, bfr[ks][0], acc[mt][0], 0, 0, 0);
            acc[mt][1] = __builtin_amdgcn_mfma_f32_16x16x32_bf16(afr, bfr[ks][1], acc[mt][1], 0, 0, 0);
        }
    }

    // ---- epilogue: BN + relu + residual(LDS) ----
#pragma unroll
    for (int nt2 = 0; nt2 < 2; ++nt2) {
        const int gcol = wid * 32 + nt2 * 16 + (lane & 15);
        const float sc = gammal[gcol] * __frsqrt_rn(rvarl[gcol] + BN_EPS);
        const float sh = (bl[gcol] - rmeanl[gcol]) * sc + betal[gcol];
        const int kc_res = 16 + (gcol >> 3);
        const int ko_res = gcol & 7;
#pragma unroll
        for (int mt = 0; mt < 4; ++mt) {
#pragma unroll
            for (int r = 0; r < 4; ++r) {
                int m = mt * 16 + (lane >> 4) * 4 + r;
                int grow = brow + m;
                if (grow < n) {
                    float res = bf2f(As[m * 256 + (kc_res ^ (m & 7)) * 8 + ko_res]);
                    float t = acc[mt][nt2][r] * sc + sh;
                    float o = res + (t > 0.f ? t : 0.f);
                    h16[(size_t)grow * DD + gcol] = f2bf(o);
                    if (write_f32) outf[(size_t)grow * DD + gcol] = o;
                }
            }
        }
    }
}

extern "C" void kernel_launch(void* const* d_in, const int* in_sizes, int n_in,
                              void* d_out, int out_size, void* d_ws, size_t ws_size,
                              hipStream_t stream) {
    const float* x     = (const float*)d_in[0];
    const int*   row   = (const int*)  d_in[1];
    const int*   col   = (const int*)  d_in[2];
    const float* ew    = (const float*)d_in[3];
    const float* W     = (const float*)d_in[4];
    const float* SW    = (const float*)d_in[5];
    const float* b     = (const float*)d_in[6];
    const float* gamma = (const float*)d_in[7];
    const float* beta  = (const float*)d_in[8];
    const float* rmean = (const float*)d_in[9];
    const float* rvar  = (const float*)d_in[10];

    float* out = (float*)d_out;

    // workspace layout (char-based offsets, all 16B-aligned where needed)
    char* ws = (char*)d_ws;
    unsigned*       agg16u = (unsigned*)ws;                              // 12.8 MB
    unsigned*       h16u   = (unsigned*)(ws + 12800000);                 // 12.8 MB
    unsigned short* Wf     = (unsigned short*)(ws + 25600000);           // 196608 B
    int*   rowptr = (int*)(ws + 25796608);                               // N+1
    int*   cursor = rowptr + NNODES + 1;
    int*   deg    = cursor + NNODES;
    int*   bsum   = deg + NNODES;
    int*   boff   = bsum + 256;
    int*   ccol   = boff + 256;                                          // E
    float* cw     = (float*)(ccol + NEDGES);                             // E

    const int egrid = (NEDGES + 255) / 256;   // 3125

    // ---- build CSR once ----
    hipMemsetAsync(deg, 0, NNODES * sizeof(int), stream);
    hist_kernel<<<egrid, 256, 0, stream>>>(row, deg, NEDGES);
    scan1_kernel<<<NBLK_SCAN, 256, 0, stream>>>(deg, rowptr, bsum, NNODES);
    scan2_kernel<<<1, 256, 0, stream>>>(bsum, boff, NBLK_SCAN);
    scan3_kernel<<<NBLK_SCAN, 256, 0, stream>>>(rowptr, boff, cursor, NNODES);
    csr_fill_kernel<<<egrid, 256, 0, stream>>>(row, col, ew, cursor, ccol, cw, NEDGES);

    // ---- converts ----
    conv_x16_kernel<<<2048, 256, 0, stream>>>(x, h16u, NNODES * 64);
    conv_wf_kernel<<<48, 256, 0, stream>>>(W, SW, Wf);

    // Only layers 0, 2, 5 are live (inner branch layers all consume the
    // branch input, so only each branch's last layer reaches the output).
    const int ggrid = (NNODES + 3) / 4;       // 12500
    const int mgrid = (NNODES + 63) / 64;     // 782

    for (int li = 0; li < 3; ++li) {
        const int l = (li == 0) ? 0 : (li == 1) ? 2 : 5;
        spmm_gather16_kernel<<<ggrid, 256, 0, stream>>>(
            h16u, rowptr, ccol, cw, agg16u, NNODES);
        gemm_mfma_kernel<<<mgrid, 256, 0, stream>>>(
            (unsigned short*)h16u, (const unsigned short*)agg16u,
            Wf + (size_t)li * 32768,
            b + l * DD, gamma + l * DD, beta + l * DD, rmean + l * DD, rvar + l * DD,
            out, NNODES, li == 2 ? 1 : 0);
    }
}